// Round 3
// baseline (283.800 us; speedup 1.0000x reference)
//
#include <hip/hip_runtime.h>

#define N_NODES 8192
#define IN_F    1024
#define OUT_F   512
#define N_EDGES 262144
#define STRIDE  96                // fixed adjacency row stride; P(deg>=96) ~ 1e-18
#define MAX_DEG STRIDE

#define GRID     512
#define NTHREADS (GRID * 256)

// ---------------- workspace layout (bytes) ----------------
#define HID_OFF     0u            // 8192*512*2   =  8,388,608  (bf16 H)
#define XB_OFF      8388608u      // 8192*1024*2  = 16,777,216  (bf16 X)
#define WB_OFF      25165824u     // 512*1024*2   =  1,048,576  (bf16 W, contiguous after Xb)
#define DEG_OFF     26214400u     // 8192*4 = 32,768
#define BAR_OFF     26247168u     // 256 B: grid-barrier counters (zeroed each launch)
#define COL_OFF     26247424u     // 8192*96*4 = 3,145,728 -> ends 29,393,152

typedef short  bf16x8 __attribute__((ext_vector_type(8)));
typedef float  f32x4  __attribute__((ext_vector_type(4)));

__device__ __forceinline__ unsigned short f2bf(float f) {
    unsigned u = __float_as_uint(f);
    u += 0x7fffu + ((u >> 16) & 1u);   // round-to-nearest-even
    return (unsigned short)(u >> 16);
}

__device__ __forceinline__ float bflo(unsigned u) { return __uint_as_float(u << 16); }
__device__ __forceinline__ float bfhi(unsigned u) { return __uint_as_float(u & 0xffff0000u); }

__device__ __forceinline__ void ld_lds16(const void* g, void* l) {
    __builtin_amdgcn_global_load_lds(
        (const __attribute__((address_space(1))) void*)g,
        (__attribute__((address_space(3))) void*)l, 16, 0, 0);
}

// device-scope grid barrier: all GRID blocks are co-resident (512 blocks,
// 48 KB LDS -> 3 blocks/CU by LDS, launch_bounds(256,2) caps VGPR<=256 ->
// 2 blocks/CU by regs; 2*256 = 512 >= GRID, so no deadlock).
// release fence + agent-scope atomics handle cross-XCD L2 writeback/inv.
__device__ __forceinline__ void gbar(int* cnt) {
    __syncthreads();
    if (threadIdx.x == 0) {
        __threadfence();                                   // release our writes
        __hip_atomic_fetch_add(cnt, 1, __ATOMIC_ACQ_REL, __HIP_MEMORY_SCOPE_AGENT);
        while (__hip_atomic_load(cnt, __ATOMIC_ACQUIRE, __HIP_MEMORY_SCOPE_AGENT) < GRID)
            __builtin_amdgcn_s_sleep(1);
        __threadfence();                                   // acquire others' writes
    }
    __syncthreads();
}

#define NX8 (N_NODES * IN_F / 8)          // 1,048,576 chunks of 8
#define NW8 (OUT_F * IN_F / 8)            //    65,536  (NX8+NW8 = 8.5 * 131072)

// =======================  single fused persistent kernel  ====================
// Phase A: edge scatter (2 edges/thread, exact) + fp32->bf16 cvt (grid-stride)
// Phase B: 128x64-tile MFMA GEMM, dbuf LDS, 1 barrier/K-step, XOR-swizzled
// Phase C: wave-per-node dedup + gather + ReLU, 4 nodes/wave, 16-deep MLP
__global__ __launch_bounds__(256, 2) void fused(const float* __restrict__ x,
                                                const float* __restrict__ w,
                                                const float* __restrict__ bias,
                                                const int* __restrict__ src,
                                                const int* __restrict__ dst,
                                                unsigned short* __restrict__ Xb,
                                                unsigned short* __restrict__ Wb,
                                                unsigned short* __restrict__ H,
                                                int* __restrict__ deg,
                                                int* __restrict__ col,
                                                int* __restrict__ bar,
                                                float* __restrict__ out) {
    __shared__ unsigned long long smem8[49152 / 8];        // 48 KB, aliased per phase
    unsigned short* As0 = (unsigned short*)smem8;          // [2][128*64] = 32 KB
    unsigned short* Bs0 = As0 + 2 * 128 * 64;              // [2][ 64*64] = 16 KB

    const int bid  = blockIdx.x;
    const int tid  = threadIdx.x;
    const int lane = tid & 63;
    const int wave = tid >> 6;

    // ---------------- phase A: scatter + cvt ----------------
    {
        const int e0 = bid * 256 + tid;            // 2 * 131072 == N_EDGES exactly
        const int e1 = e0 + NTHREADS;
        const int s0 = src[e0], d0 = dst[e0];
        const int s1 = src[e1], d1 = dst[e1];
        int sl0 = atomicAdd(&deg[s0], 1);
        if (sl0 < STRIDE) col[s0 * STRIDE + sl0] = d0;
        int sl1 = atomicAdd(&deg[s1], 1);
        if (sl1 < STRIDE) col[s1 * STRIDE + sl1] = d1;

        for (int i = e0; i < NX8 + NW8; i += NTHREADS) {
            const f32x4* p = (i < NX8) ? ((const f32x4*)x + (size_t)i * 2)
                                       : ((const f32x4*)w + (size_t)(i - NX8) * 2);
            f32x4 v0 = __builtin_nontemporal_load(p);      // x/w never re-read as fp32
            f32x4 v1 = __builtin_nontemporal_load(p + 1);
            uint4 o;
            o.x = (unsigned)f2bf(v0.x) | ((unsigned)f2bf(v0.y) << 16);
            o.y = (unsigned)f2bf(v0.z) | ((unsigned)f2bf(v0.w) << 16);
            o.z = (unsigned)f2bf(v1.x) | ((unsigned)f2bf(v1.y) << 16);
            o.w = (unsigned)f2bf(v1.z) | ((unsigned)f2bf(v1.w) << 16);
            *((uint4*)Xb + i) = o;                         // Wb contiguous after Xb
        }
    }
    gbar(&bar[0]);

    // ---------------- phase B: GEMM ----------------
    {
        const int row0 = (bid & 63) * 128;        // 64 row-tiles
        const int col0 = (bid >> 6) * 64;         // 8 col-tiles
        const int wm   = (wave & 1) * 64;
        const int wn   = (wave >> 1) * 32;
        const int fm   = lane & 15;
        const int fm7  = fm & 7;
        const int q    = lane >> 4;               // k-quad within the 32-k MFMA window

        f32x4 acc[4][2];
#pragma unroll
        for (int i = 0; i < 4; ++i)
#pragma unroll
            for (int j = 0; j < 2; ++j) acc[i][j] = (f32x4)0.f;

        // staging: slot=tid covers (r=tid>>3, swizzled k-chunk); +256 -> r+32, ...
        const int r0 = tid >> 3;                              // 0..31
        const int kp = ((tid & 7) ^ (r0 & 7)) * 8;            // swizzled k elem-offset
        const unsigned short* Xbase = Xb + (size_t)(row0 + r0) * IN_F + kp;
        const unsigned short* Wbase = Wb + (size_t)(col0 + r0) * IN_F + kp;

#define STAGE(buf, k0) do {                                                   \
    unsigned short* A_ = As0 + (buf) * (128 * 64);                            \
    unsigned short* B_ = Bs0 + (buf) * (64 * 64);                             \
    ld_lds16(Xbase            + (k0), A_ + tid * 8);                          \
    ld_lds16(Xbase + 32*IN_F  + (k0), A_ + (tid + 256) * 8);                  \
    ld_lds16(Xbase + 64*IN_F  + (k0), A_ + (tid + 512) * 8);                  \
    ld_lds16(Xbase + 96*IN_F  + (k0), A_ + (tid + 768) * 8);                  \
    ld_lds16(Wbase            + (k0), B_ + tid * 8);                          \
    ld_lds16(Wbase + 32*IN_F  + (k0), B_ + (tid + 256) * 8);                  \
} while (0)

#define COMPUTE(buf) do {                                                     \
    const unsigned short* A_ = As0 + (buf) * (128 * 64);                      \
    const unsigned short* B_ = Bs0 + (buf) * (64 * 64);                       \
    _Pragma("unroll")                                                         \
    for (int s = 0; s < 2; ++s) {                                             \
        const int kq = s * 4 + q;                                             \
        bf16x8 a[4], b[2];                                                    \
        _Pragma("unroll")                                                     \
        for (int mi = 0; mi < 4; ++mi)                                        \
            a[mi] = *(const bf16x8*)&A_[(((wm + mi*16 + fm) << 3) + (kq ^ fm7)) << 3]; \
        _Pragma("unroll")                                                     \
        for (int ni = 0; ni < 2; ++ni)                                        \
            b[ni] = *(const bf16x8*)&B_[(((wn + ni*16 + fm) << 3) + (kq ^ fm7)) << 3]; \
        _Pragma("unroll")                                                     \
        for (int mi = 0; mi < 4; ++mi)                                        \
            _Pragma("unroll")                                                 \
            for (int ni = 0; ni < 2; ++ni)                                    \
                acc[mi][ni] = __builtin_amdgcn_mfma_f32_16x16x32_bf16(        \
                    a[mi], b[ni], acc[mi][ni], 0, 0, 0);                      \
    }                                                                         \
} while (0)

        STAGE(0, 0);
        __syncthreads();                          // drain prologue stage
        int cur = 0;
        for (int t = 0; t < 15; ++t) {
            STAGE(cur ^ 1, (t + 1) * 64);         // prefetch next K-tile (other buffer)
            COMPUTE(cur);                         // MFMA overlaps the in-flight loads
            __syncthreads();                      // one barrier/K-step (drains vmcnt)
            cur ^= 1;
        }
        COMPUTE(cur);                             // last tile, nothing left to stage

        const int cm = (lane >> 4) * 4;   // C/D: col = lane&15, row = (lane>>4)*4 + reg
#pragma unroll
        for (int ni = 0; ni < 2; ++ni) {
            const int c = col0 + wn + ni * 16 + fm;
            const float bv = bias[c];
#pragma unroll
            for (int mi = 0; mi < 4; ++mi) {
#pragma unroll
                for (int r = 0; r < 4; ++r) {
                    const int row = row0 + wm + mi * 16 + cm + r;
                    H[(size_t)row * OUT_F + c] = f2bf(acc[mi][ni][r] + bv);
                }
            }
        }
#undef STAGE
#undef COMPUTE
    }
    gbar(&bar[1]);

    // ---------------- phase C: aggregate ----------------
    {
        int* nbr  = (int*)smem8;                  // [4][MAX_DEG]
        int* uniq = nbr + 4 * MAX_DEG;            // [4][MAX_DEG]
        int* wcnt = uniq + 4 * MAX_DEG;           // [4]
        int* mynbr = nbr  + wave * MAX_DEG;
        int* myuq  = uniq + wave * MAX_DEG;
        const int f0 = lane * 8;                  // lane covers 8 feats (uint4)

        for (int rnd = 0; rnd < 4; ++rnd) {
            const int v = bid * 16 + wave * 4 + rnd;   // block covers 16 consecutive nodes
            int d = deg[v];
            if (d > MAX_DEG) d = MAX_DEG;

            if (lane == 0) wcnt[wave] = 0;
            int id0 = -1, id1 = -1;
            if (lane < d)      { id0 = col[v * STRIDE + lane];      mynbr[lane]      = id0; }
            if (64 + lane < d) { id1 = col[v * STRIDE + 64 + lane]; mynbr[64 + lane] = id1; }
            __builtin_amdgcn_wave_barrier();   // wave-synchronous LDS hand-off

            // keep entry i iff no j<i equals it (no early exit -> LDS reads pipeline)
            bool k0 = (lane < d);
            const int lim0 = k0 ? lane : 0;
            for (int j = 0; j < lim0; ++j) k0 = k0 & (mynbr[j] != id0);
            bool k1 = (64 + lane < d);
            const int lim1 = k1 ? (64 + lane) : 0;
            for (int j = 0; j < lim1; ++j) k1 = k1 & (mynbr[j] != id1);
            if (k0) myuq[atomicAdd(&wcnt[wave], 1)] = id0;
            if (k1) myuq[atomicAdd(&wcnt[wave], 1)] = id1;
            __builtin_amdgcn_wave_barrier();
            const int n = wcnt[wave];

            float a0=0,a1=0,a2=0,a3=0,a4=0,a5=0,a6=0,a7=0;
            int e = 0;
            for (; e + 16 <= n; e += 16) {        // 16 rows in flight (latency-bound)
                uint4 h[16];
#pragma unroll
                for (int t = 0; t < 16; ++t)
                    h[t] = *(const uint4*)&H[(size_t)myuq[e + t] * OUT_F + f0];
#pragma unroll
                for (int t = 0; t < 16; ++t) {
                    a0 += bflo(h[t].x); a1 += bfhi(h[t].x);
                    a2 += bflo(h[t].y); a3 += bfhi(h[t].y);
                    a4 += bflo(h[t].z); a5 += bfhi(h[t].z);
                    a6 += bflo(h[t].w); a7 += bfhi(h[t].w);
                }
            }
            for (; e + 4 <= n; e += 4) {
                uint4 h[4];
#pragma unroll
                for (int t = 0; t < 4; ++t)
                    h[t] = *(const uint4*)&H[(size_t)myuq[e + t] * OUT_F + f0];
#pragma unroll
                for (int t = 0; t < 4; ++t) {
                    a0 += bflo(h[t].x); a1 += bfhi(h[t].x);
                    a2 += bflo(h[t].y); a3 += bfhi(h[t].y);
                    a4 += bflo(h[t].z); a5 += bfhi(h[t].z);
                    a6 += bflo(h[t].w); a7 += bfhi(h[t].w);
                }
            }
            for (; e < n; ++e) {
                uint4 h0 = *(const uint4*)&H[(size_t)myuq[e] * OUT_F + f0];
                a0 += bflo(h0.x); a1 += bfhi(h0.x);
                a2 += bflo(h0.y); a3 += bfhi(h0.y);
                a4 += bflo(h0.z); a5 += bfhi(h0.z);
                a6 += bflo(h0.w); a7 += bfhi(h0.w);
            }
            f32x4 o0 = {fmaxf(a0,0.f), fmaxf(a1,0.f), fmaxf(a2,0.f), fmaxf(a3,0.f)};
            f32x4 o1 = {fmaxf(a4,0.f), fmaxf(a5,0.f), fmaxf(a6,0.f), fmaxf(a7,0.f)};
            // out is never re-read -> nontemporal, keep L2 for the H gather
            __builtin_nontemporal_store(o0, (f32x4*)&out[(size_t)v * OUT_F + f0]);
            __builtin_nontemporal_store(o1, (f32x4*)&out[(size_t)v * OUT_F + f0 + 4]);
        }
    }
}

extern "C" void kernel_launch(void* const* d_in, const int* in_sizes, int n_in,
                              void* d_out, int out_size, void* d_ws, size_t ws_size,
                              hipStream_t stream) {
    const float* x  = (const float*)d_in[0];
    const float* W  = (const float*)d_in[1];
    const float* b  = (const float*)d_in[2];
    const int*   ei = (const int*)d_in[3];      // [2, N_EDGES]: src then dst
    float* out = (float*)d_out;

    char* ws = (char*)d_ws;
    unsigned short* H   = (unsigned short*)(ws + HID_OFF);
    unsigned short* Xb  = (unsigned short*)(ws + XB_OFF);   // Wb contiguous after
    unsigned short* Wb  = (unsigned short*)(ws + WB_OFF);
    int*            deg = (int*)(ws + DEG_OFF);
    int*            bar = (int*)(ws + BAR_OFF);
    int*            col = (int*)(ws + COL_OFF);

    // zero deg + barrier counters (stream-ordered, graph-capture legal)
    hipMemsetAsync(ws + DEG_OFF, 0, (BAR_OFF - DEG_OFF) + 256, stream);

    // one persistent kernel: scatter+cvt | gbar | GEMM | gbar | aggregate
    fused<<<GRID, 256, 0, stream>>>(x, W, b, ei, ei + N_EDGES,
                                    Xb, Wb, H, deg, col, bar, out);
}

// Round 4
// 138.869 us; speedup vs baseline: 2.0437x; 2.0437x over previous
//
#include <hip/hip_runtime.h>

#define N_NODES 8192
#define IN_F    1024
#define OUT_F   512
#define N_EDGES 262144
#define STRIDE  96                // fixed adjacency row stride; P(deg>=96) ~ 1e-18

// ---------------- workspace layout (bytes) ----------------
#define HID_OFF     0u            // 8192*512*2   =  8,388,608  (bf16 H)
#define XB_OFF      8388608u      // 8192*1024*2  = 16,777,216  (bf16 X)
#define WB_OFF      25165824u     // 512*1024*2   =  1,048,576  (bf16 W, contiguous after Xb)
#define DEG_OFF     26214400u     // 8192*4 = 32,768
#define COL_OFF     26247168u     // 8192*96*4 = 3,145,728 -> ends 29,392,896
#define MAX_DEG     STRIDE

typedef short  bf16x8 __attribute__((ext_vector_type(8)));
typedef float  f32x4  __attribute__((ext_vector_type(4)));

__device__ __forceinline__ unsigned short f2bf(float f) {
    unsigned u = __float_as_uint(f);
    u += 0x7fffu + ((u >> 16) & 1u);   // round-to-nearest-even
    return (unsigned short)(u >> 16);
}

__device__ __forceinline__ float bflo(unsigned u) { return __uint_as_float(u << 16); }
__device__ __forceinline__ float bfhi(unsigned u) { return __uint_as_float(u & 0xffff0000u); }

__device__ __forceinline__ void ld_lds16(const void* g, void* l) {
    __builtin_amdgcn_global_load_lds(
        (const __attribute__((address_space(1))) void*)g,
        (__attribute__((address_space(3))) void*)l, 16, 0, 0);
}

// --- fp32 -> bf16 for X and W in one launch; first 8192 threads zero deg ---
#define NX8 (N_NODES * IN_F / 8)          // 1,048,576 chunks of 8
#define NW8 (OUT_F * IN_F / 8)            //    65,536
__global__ __launch_bounds__(256) void cvt_bf16_all(const float* __restrict__ x,
                                                    const float* __restrict__ w,
                                                    unsigned short* __restrict__ xb,
                                                    int* __restrict__ deg) {
    int i = blockIdx.x * blockDim.x + threadIdx.x;
    if (i < N_NODES) deg[i] = 0;
    if (i >= NX8 + NW8) return;
    const f32x4* p = (i < NX8) ? ((const f32x4*)x + (size_t)i * 2)
                               : ((const f32x4*)w + (size_t)(i - NX8) * 2);
    f32x4 v0 = __builtin_nontemporal_load(p);      // x/w not re-read as fp32
    f32x4 v1 = __builtin_nontemporal_load(p + 1);
    uint4 o;
    o.x = (unsigned)f2bf(v0.x) | ((unsigned)f2bf(v0.y) << 16);
    o.y = (unsigned)f2bf(v0.z) | ((unsigned)f2bf(v0.w) << 16);
    o.z = (unsigned)f2bf(v1.x) | ((unsigned)f2bf(v1.y) << 16);
    o.w = (unsigned)f2bf(v1.z) | ((unsigned)f2bf(v1.w) << 16);
    *((uint4*)xb + i) = o;
}

// ------- fused: MFMA GEMM (blocks 0..511) + edge scatter (512..1535) -----
// GEMM: 128x64 tile, BK=64 (16 iters), 4 waves (2m x 2n), wave = 64x32 out.
// Double-buffered LDS, ONE barrier per K-step.  LDS XOR-swizzle: logical
// chunk (row,kq) lives at slot row*8+(kq^(row&7)); global_load_lds forces
// slot=lane, so the swizzle is applied by permuting the GLOBAL chunk each
// lane fetches (permutation stays within 128 B -> coalescing preserved).
// Scatter blocks (no LDS, 4 waves) co-schedule onto the free wave slots of
// CUs holding GEMM blocks (8 GEMM waves + up to 24 scatter waves per CU),
// so the latency-bound scatter hides under the MFMA-bound GEMM.
#define GEMM_BLOCKS 512

__global__ __launch_bounds__(256, 2) void gemm_scatter(const unsigned short* __restrict__ Xb,
                                                       const unsigned short* __restrict__ Wb,
                                                       const float* __restrict__ bias,
                                                       unsigned short* __restrict__ H,
                                                       const int* __restrict__ src,
                                                       const int* __restrict__ dst,
                                                       int* __restrict__ deg,
                                                       int* __restrict__ col) {
    __shared__ unsigned short As[2][128 * 64];   // 32 KB
    __shared__ unsigned short Bs[2][64 * 64];    // 16 KB

    const int bid = blockIdx.x;
    const int tid = threadIdx.x;

    if (bid >= GEMM_BLOCKS) {                 // ---- scatter part ----
        int e = (bid - GEMM_BLOCKS) * 256 + tid;   // 1024*256 == N_EDGES exactly
        int s = src[e];
        int slot = atomicAdd(&deg[s], 1);
        if (slot < STRIDE) col[s * STRIDE + slot] = dst[e];
        return;
    }

    // ---- GEMM part ----
    const int lane = tid & 63;
    const int wave = tid >> 6;
    const int row0 = (bid & 63) * 128;        // 64 row-tiles
    const int col0 = (bid >> 6) * 64;         // 8 col-tiles
    const int wm   = (wave & 1) * 64;
    const int wn   = (wave >> 1) * 32;
    const int fm   = lane & 15;
    const int fm7  = fm & 7;
    const int q    = lane >> 4;               // k-quad within the 32-k MFMA window

    f32x4 acc[4][2];
#pragma unroll
    for (int i = 0; i < 4; ++i)
#pragma unroll
        for (int j = 0; j < 2; ++j) acc[i][j] = (f32x4)0.f;

    // staging: slot = tid covers (r = tid>>3, swizzled k-chunk); +256 -> r+32, ...
    const int r0 = tid >> 3;                              // 0..31
    const int kp = ((tid & 7) ^ (r0 & 7)) * 8;            // swizzled k elem-offset
    const unsigned short* Xbase = Xb + (size_t)(row0 + r0) * IN_F + kp;
    const unsigned short* Wbase = Wb + (size_t)(col0 + r0) * IN_F + kp;

#define STAGE(buf, k0) do {                                                   \
    ld_lds16(Xbase            + (k0), &As[buf][tid * 8]);                     \
    ld_lds16(Xbase + 32*IN_F  + (k0), &As[buf][(tid + 256) * 8]);             \
    ld_lds16(Xbase + 64*IN_F  + (k0), &As[buf][(tid + 512) * 8]);             \
    ld_lds16(Xbase + 96*IN_F  + (k0), &As[buf][(tid + 768) * 8]);             \
    ld_lds16(Wbase            + (k0), &Bs[buf][tid * 8]);                     \
    ld_lds16(Wbase + 32*IN_F  + (k0), &Bs[buf][(tid + 256) * 8]);             \
} while (0)

#define COMPUTE(buf) do {                                                     \
    _Pragma("unroll")                                                         \
    for (int s = 0; s < 2; ++s) {                                             \
        const int kq = s * 4 + q;                                             \
        bf16x8 a[4], b[2];                                                    \
        _Pragma("unroll")                                                     \
        for (int mi = 0; mi < 4; ++mi)                                        \
            a[mi] = *(const bf16x8*)&As[buf][(((wm + mi*16 + fm) << 3) + (kq ^ fm7)) << 3]; \
        _Pragma("unroll")                                                     \
        for (int ni = 0; ni < 2; ++ni)                                        \
            b[ni] = *(const bf16x8*)&Bs[buf][(((wn + ni*16 + fm) << 3) + (kq ^ fm7)) << 3]; \
        _Pragma("unroll")                                                     \
        for (int mi = 0; mi < 4; ++mi)                                        \
            _Pragma("unroll")                                                 \
            for (int ni = 0; ni < 2; ++ni)                                    \
                acc[mi][ni] = __builtin_amdgcn_mfma_f32_16x16x32_bf16(        \
                    a[mi], b[ni], acc[mi][ni], 0, 0, 0);                      \
    }                                                                         \
} while (0)

    STAGE(0, 0);
    __syncthreads();                          // drain prologue stage
    int cur = 0;
    for (int t = 0; t < 15; ++t) {
        STAGE(cur ^ 1, (t + 1) * 64);         // prefetch next K-tile (other buffer)
        COMPUTE(cur);                         // MFMA on current tile overlaps the loads
        __syncthreads();                      // one barrier/K-step: drains vmcnt + sync
        cur ^= 1;
    }
    COMPUTE(cur);                             // last tile, nothing left to stage

    const int cm = (lane >> 4) * 4;   // C/D: col = lane&15, row = (lane>>4)*4 + reg
#pragma unroll
    for (int ni = 0; ni < 2; ++ni) {
        const int c = col0 + wn + ni * 16 + fm;
        const float bv = bias[c];
#pragma unroll
        for (int mi = 0; mi < 4; ++mi) {
#pragma unroll
            for (int r = 0; r < 4; ++r) {
                const int row = row0 + wm + mi * 16 + cm + r;
                H[(size_t)row * OUT_F + c] = f2bf(acc[mi][ni][r] + bv);
            }
        }
    }
#undef STAGE
#undef COMPUTE
}

// ---- aggregate: wave per (node, feature-half). lane covers 4 feats (uint2). ----
// The gather is outstanding-bytes-bound (R3 evidence: phase C at 8 waves/CU ran
// 1.5 TB/s; at ~16 waves/CU ~6 TB/s).  Feature-split halves per-wave VGPR state
// so launch_bounds(256,8) holds VGPR <= 64 -> 8 waves/SIMD = 32 waves/CU, and a
// 12-deep MLP keeps 192 KB/CU outstanding with zero spill risk.
__global__ __launch_bounds__(256, 8) void aggregate(const unsigned short* __restrict__ H,
                                                    const int* __restrict__ dg,
                                                    const int* __restrict__ col,
                                                    float* __restrict__ out) {
    __shared__ int nbr[4][MAX_DEG];
    __shared__ int uniq[4][MAX_DEG];
    __shared__ int wcnt[4];
    const int wave = threadIdx.x >> 6;
    const int lane = threadIdx.x & 63;
    const int task = blockIdx.x * 4 + wave;
    const int v    = task >> 1;           // node
    const int half = task & 1;            // feature half (0: 0..255, 1: 256..511)
    int d = dg[v];
    if (d > MAX_DEG) d = MAX_DEG;

    if (lane == 0) wcnt[wave] = 0;
    int id0 = -1, id1 = -1;
    if (lane < d)      { id0 = col[v * STRIDE + lane];      nbr[wave][lane]      = id0; }
    if (64 + lane < d) { id1 = col[v * STRIDE + 64 + lane]; nbr[wave][64 + lane] = id1; }
    __builtin_amdgcn_wave_barrier();   // wave-synchronous; pin scheduling across LDS use

    // keep entry i iff no j<i equals it (no early exit -> LDS reads pipeline)
    bool k0 = (lane < d);
    const int lim0 = k0 ? lane : 0;
    for (int j = 0; j < lim0; ++j) k0 = k0 & (nbr[wave][j] != id0);
    bool k1 = (64 + lane < d);
    const int lim1 = k1 ? (64 + lane) : 0;
    for (int j = 0; j < lim1; ++j) k1 = k1 & (nbr[wave][j] != id1);
    if (k0) uniq[wave][atomicAdd(&wcnt[wave], 1)] = id0;
    if (k1) uniq[wave][atomicAdd(&wcnt[wave], 1)] = id1;
    __builtin_amdgcn_wave_barrier();
    const int n  = wcnt[wave];
    const int* uq = &uniq[wave][0];
    // lane covers 4 feats of this half: 64 lanes x 8 B = 512 B contiguous per row
    const unsigned short* Hh = H + half * 256 + lane * 4;

    float a0=0,a1=0,a2=0,a3=0;
    int e = 0;
    for (; e + 12 <= n; e += 12) {        // 12 rows in flight (24 VGPR of data)
        uint2 h[12];
#pragma unroll
        for (int t = 0; t < 12; ++t)
            h[t] = *(const uint2*)&Hh[(size_t)uq[e + t] * OUT_F];
#pragma unroll
        for (int t = 0; t < 12; ++t) {
            a0 += bflo(h[t].x); a1 += bfhi(h[t].x);
            a2 += bflo(h[t].y); a3 += bfhi(h[t].y);
        }
    }
    for (; e + 4 <= n; e += 4) {
        uint2 h[4];
#pragma unroll
        for (int t = 0; t < 4; ++t)
            h[t] = *(const uint2*)&Hh[(size_t)uq[e + t] * OUT_F];
#pragma unroll
        for (int t = 0; t < 4; ++t) {
            a0 += bflo(h[t].x); a1 += bfhi(h[t].x);
            a2 += bflo(h[t].y); a3 += bfhi(h[t].y);
        }
    }
    for (; e < n; ++e) {
        uint2 h0 = *(const uint2*)&Hh[(size_t)uq[e] * OUT_F];
        a0 += bflo(h0.x); a1 += bfhi(h0.x);
        a2 += bflo(h0.y); a3 += bfhi(h0.y);
    }
    f32x4 o = {fmaxf(a0,0.f), fmaxf(a1,0.f), fmaxf(a2,0.f), fmaxf(a3,0.f)};
    // out is never re-read -> nontemporal, keep L2/L3 for the H gather
    __builtin_nontemporal_store(o, (f32x4*)&out[(size_t)v * OUT_F + half * 256 + lane * 4]);
}

extern "C" void kernel_launch(void* const* d_in, const int* in_sizes, int n_in,
                              void* d_out, int out_size, void* d_ws, size_t ws_size,
                              hipStream_t stream) {
    const float* x  = (const float*)d_in[0];
    const float* W  = (const float*)d_in[1];
    const float* b  = (const float*)d_in[2];
    const int*   ei = (const int*)d_in[3];      // [2, N_EDGES]: src then dst
    float* out = (float*)d_out;

    char* ws = (char*)d_ws;
    unsigned short* H   = (unsigned short*)(ws + HID_OFF);
    unsigned short* Xb  = (unsigned short*)(ws + XB_OFF);   // Wb contiguous after
    unsigned short* Wb  = (unsigned short*)(ws + WB_OFF);
    int*            deg = (int*)(ws + DEG_OFF);
    int*            col = (int*)(ws + COL_OFF);

    // 1) convert X,W to bf16 + zero deg
    cvt_bf16_all<<<(NX8 + NW8 + 255) / 256, 256, 0, stream>>>(x, W, Xb, deg);

    // 2) GEMM (512 blocks, 128x64 tile, dbuf) + edge scatter (1024 blocks) fused
    gemm_scatter<<<GEMM_BLOCKS + N_EDGES / 256, 256, 0, stream>>>(
        Xb, Wb, b, H, ei, ei + N_EDGES, deg, col);

    // 3) wave per (node, feature-half): 16384 tasks, 32 waves/CU, 12-deep MLP
    aggregate<<<N_NODES * 2 / 4, 256, 0, stream>>>(H, deg, col, out);
}